// Round 1
// baseline (121.030 us; speedup 1.0000x reference)
//
#include <hip/hip_runtime.h>
#include <math.h>

#define T_LEN 2048
#define C_CH  64
#define B_N   8

// ---------------------------------------------------------------------------
// Kernel 1: per-(b,c) Hilbert transform via in-LDS Stockham radix-2 FFT,
// then write unit phasors (cos(phase), sin(phase)) to workspace.
// Faithful to reference: spec[k] *= 2 for k < n/2, spec[k] = 0 for k >= n/2.
// The 1/N ifft scale cancels in the phasor normalization and is skipped.
// ---------------------------------------------------------------------------
__global__ __launch_bounds__(256) void hilbert_phasor_kernel(
    const float* __restrict__ x, float2* __restrict__ phasor) {
  __shared__ float2 bufA[T_LEN];
  __shared__ float2 bufB[T_LEN];

  const int bc = blockIdx.x;              // 0 .. B*C-1
  const float* sig = x + (size_t)bc * T_LEN;

  for (int t = threadIdx.x; t < T_LEN; t += 256)
    bufA[t] = make_float2(sig[t], 0.0f);
  __syncthreads();

  float2* src = bufA;
  float2* dst = bufB;

  // ---- forward FFT (sign = -1), Stockham DIF, self-sorting ----
  for (int n = T_LEN, s = 1, ls = 0; n >= 2; n >>= 1, s <<= 1, ++ls) {
    const int m = n >> 1;
    const float theta0 = -6.28318530717958647692f / (float)n;
    for (int idx = threadIdx.x; idx < T_LEN / 2; idx += 256) {
      const int p = idx >> ls;
      const int q = idx & (s - 1);
      const float ang = theta0 * (float)p;
      float sn, cs;
      __sincosf(ang, &sn, &cs);           // fast; precision ~2^-21, plenty
      const float2 a = src[q + s * p];
      const float2 b = src[q + s * (p + m)];
      const float2 sum = make_float2(a.x + b.x, a.y + b.y);
      const float2 dif = make_float2(a.x - b.x, a.y - b.y);
      dst[q + s * (2 * p)]     = sum;
      dst[q + s * (2 * p + 1)] = make_float2(dif.x * cs - dif.y * sn,
                                             dif.x * sn + dif.y * cs);
    }
    __syncthreads();
    float2* tmp = src; src = dst; dst = tmp;
  }

  // ---- analytic-signal filter: k < 1024 -> *2, else -> 0 ----
  for (int k = threadIdx.x; k < T_LEN; k += 256) {
    const float f = (k < T_LEN / 2) ? 2.0f : 0.0f;
    src[k].x *= f;
    src[k].y *= f;
  }
  __syncthreads();

  // ---- inverse FFT (sign = +1); global 1/N scale skipped (cancels) ----
  for (int n = T_LEN, s = 1, ls = 0; n >= 2; n >>= 1, s <<= 1, ++ls) {
    const int m = n >> 1;
    const float theta0 = 6.28318530717958647692f / (float)n;
    for (int idx = threadIdx.x; idx < T_LEN / 2; idx += 256) {
      const int p = idx >> ls;
      const int q = idx & (s - 1);
      const float ang = theta0 * (float)p;
      float sn, cs;
      __sincosf(ang, &sn, &cs);
      const float2 a = src[q + s * p];
      const float2 b = src[q + s * (p + m)];
      const float2 sum = make_float2(a.x + b.x, a.y + b.y);
      const float2 dif = make_float2(a.x - b.x, a.y - b.y);
      dst[q + s * (2 * p)]     = sum;
      dst[q + s * (2 * p + 1)] = make_float2(dif.x * cs - dif.y * sn,
                                             dif.x * sn + dif.y * cs);
    }
    __syncthreads();
    float2* tmp = src; src = dst; dst = tmp;
  }

  // ---- unit phasors ----
  for (int t = threadIdx.x; t < T_LEN; t += 256) {
    const float2 z = src[t];
    const float mag2 = z.x * z.x + z.y * z.y;
    float u, v;
    if (mag2 > 0.0f) {
      const float inv = rsqrtf(mag2);
      u = z.x * inv;
      v = z.y * inv;
    } else {           // angle(0) = 0 in numpy
      u = 1.0f;
      v = 0.0f;
    }
    phasor[(size_t)bc * T_LEN + t] = make_float2(u, v);
  }
}

// ---------------------------------------------------------------------------
// Kernel 2: one block per (b, i, j); i < j does the work, writes (i,j) & (j,i).
// sin(phi_i - phi_j) = v_i*u_j - u_i*v_j. wpli = |sum s| / sum |s| (T cancels).
// ---------------------------------------------------------------------------
__global__ __launch_bounds__(256) void wpli_pair_kernel(
    const float2* __restrict__ phasor, float* __restrict__ out) {
  const int blk = blockIdx.x;
  const int b  = blk >> 12;               // 64*64 = 4096 blocks per batch
  const int ij = blk & 4095;
  const int i  = ij >> 6;
  const int j  = ij & 63;
  if (i >= j) return;                     // block-uniform early exit

  const float2* pi = phasor + ((size_t)(b * C_CH + i)) * T_LEN;
  const float2* pj = phasor + ((size_t)(b * C_CH + j)) * T_LEN;

  float num = 0.0f, den = 0.0f;
  for (int t = threadIdx.x; t < T_LEN; t += 256) {
    const float2 zi = pi[t];
    const float2 zj = pj[t];
    const float s = zi.y * zj.x - zi.x * zj.y;
    num += s;
    den += fabsf(s);
  }

  // 64-lane wave reduce, then cross-wave via LDS
  for (int off = 32; off > 0; off >>= 1) {
    num += __shfl_down(num, off, 64);
    den += __shfl_down(den, off, 64);
  }
  __shared__ float red[8];
  const int lane = threadIdx.x & 63;
  const int wave = threadIdx.x >> 6;
  if (lane == 0) { red[wave * 2] = num; red[wave * 2 + 1] = den; }
  __syncthreads();
  if (threadIdx.x == 0) {
    float n2 = 0.0f, d2 = 0.0f;
    for (int w = 0; w < 4; ++w) { n2 += red[w * 2]; d2 += red[w * 2 + 1]; }
    const float wv = (d2 > 0.0f) ? fabsf(n2) / d2 : 0.0f;
    out[((size_t)b * C_CH + i) * C_CH + j] = wv;
    out[((size_t)b * C_CH + j) * C_CH + i] = wv;
  }
}

extern "C" void kernel_launch(void* const* d_in, const int* in_sizes, int n_in,
                              void* d_out, int out_size, void* d_ws, size_t ws_size,
                              hipStream_t stream) {
  const float* eeg = (const float*)d_in[0];
  float* out = (float*)d_out;
  float2* phasor = (float2*)d_ws;        // B*C*T float2 = 8 MB

  // zero entire output (sets the diagonal; off-diagonals overwritten)
  hipMemsetAsync(d_out, 0, (size_t)out_size * sizeof(float), stream);

  hilbert_phasor_kernel<<<B_N * C_CH, 256, 0, stream>>>(eeg, phasor);
  wpli_pair_kernel<<<B_N * C_CH * C_CH, 256, 0, stream>>>(phasor, out);
}

// Round 2
// 104.228 us; speedup vs baseline: 1.1612x; 1.1612x over previous
//
#include <hip/hip_runtime.h>
#include <math.h>

#define T_LEN 2048
#define C_CH  64
#define B_N   8

// ---------------------------------------------------------------------------
// Radix-4 Stockham butterfly helpers
// ---------------------------------------------------------------------------
__device__ __forceinline__ float2 cadd(float2 a, float2 b) { return make_float2(a.x + b.x, a.y + b.y); }
__device__ __forceinline__ float2 csub(float2 a, float2 b) { return make_float2(a.x - b.x, a.y - b.y); }

template <int SIGN>  // -1 = forward, +1 = inverse
__device__ __forceinline__ void fft_stages(float2*& src, float2*& dst, int tid) {
  // 5 radix-4 stages: n = 2048, 512, 128, 32, 8
  for (int n = T_LEN, ls = 0; n >= 4; n >>= 2, ls += 2) {
    const int s = 1 << ls;
    const int m = n >> 2;
    const float th = (float)SIGN * 6.28318530717958647692f / (float)n;
    for (int idx = tid; idx < T_LEN / 4; idx += 256) {
      const int p = idx >> ls;
      const int q = idx & (s - 1);
      const int base = q + s * p;
      const float2 a = src[base];
      const float2 b = src[base + s * m];
      const float2 c = src[base + 2 * s * m];
      const float2 d = src[base + 3 * s * m];
      const float2 t0 = cadd(a, c);
      const float2 t1 = csub(a, c);
      const float2 t2 = cadd(b, d);
      const float2 t3 = csub(b, d);
      const float2 y0 = cadd(t0, t2);
      const float2 r2 = csub(t0, t2);
      float2 r1, r3;
      if (SIGN < 0) {           // forward: r1 = t1 - i*t3, r3 = t1 + i*t3
        r1 = make_float2(t1.x + t3.y, t1.y - t3.x);
        r3 = make_float2(t1.x - t3.y, t1.y + t3.x);
      } else {                  // inverse: r1 = t1 + i*t3, r3 = t1 - i*t3
        r1 = make_float2(t1.x - t3.y, t1.y + t3.x);
        r3 = make_float2(t1.x + t3.y, t1.y - t3.x);
      }
      const float pf = (float)p;
      float s1, c1, s2, c2, s3, c3;
      __sincosf(th * pf, &s1, &c1);
      __sincosf(2.0f * th * pf, &s2, &c2);
      __sincosf(3.0f * th * pf, &s3, &c3);
      const float2 y1 = make_float2(r1.x * c1 - r1.y * s1, r1.x * s1 + r1.y * c1);
      const float2 y2 = make_float2(r2.x * c2 - r2.y * s2, r2.x * s2 + r2.y * c2);
      const float2 y3 = make_float2(r3.x * c3 - r3.y * s3, r3.x * s3 + r3.y * c3);
      const int ob = q + s * 4 * p;
      dst[ob]         = y0;
      dst[ob + s]     = y1;
      dst[ob + 2 * s] = y2;
      dst[ob + 3 * s] = y3;
    }
    __syncthreads();
    float2* tmp = src; src = dst; dst = tmp;
  }
  // final radix-2 stage: n = 2, s = 1024, twiddle = 1
  for (int q = tid; q < T_LEN / 2; q += 256) {
    const float2 a = src[q];
    const float2 b = src[q + T_LEN / 2];
    dst[q]             = cadd(a, b);
    dst[q + T_LEN / 2] = csub(a, b);
  }
  __syncthreads();
  float2* tmp = src; src = dst; dst = tmp;
}

// ---------------------------------------------------------------------------
// Kernel 1: per-(b,c) Hilbert via radix-4 LDS FFT; writes unit phasors.
// Reference-faithful filter: spec[k<1024] *= 2, spec[k>=1024] = 0.
// The 1/N ifft scale cancels in the phasor normalization.
// ---------------------------------------------------------------------------
__global__ __launch_bounds__(256) void hilbert_phasor_kernel(
    const float* __restrict__ x, float2* __restrict__ phasor) {
  __shared__ float2 bufA[T_LEN];
  __shared__ float2 bufB[T_LEN];

  const int bc = blockIdx.x;
  const int tid = threadIdx.x;
  const float* sig = x + (size_t)bc * T_LEN;

  for (int t = tid; t < T_LEN; t += 256)
    bufA[t] = make_float2(sig[t], 0.0f);
  __syncthreads();

  float2* src = bufA;
  float2* dst = bufB;

  fft_stages<-1>(src, dst, tid);        // forward FFT (result in src)

  for (int k = tid; k < T_LEN; k += 256) {
    const float f = (k < T_LEN / 2) ? 2.0f : 0.0f;
    src[k].x *= f;
    src[k].y *= f;
  }
  __syncthreads();

  fft_stages<1>(src, dst, tid);         // inverse FFT (unscaled)

  for (int t = tid; t < T_LEN; t += 256) {
    const float2 z = src[t];
    const float mag2 = z.x * z.x + z.y * z.y;
    float u, v;
    if (mag2 > 0.0f) {
      const float inv = rsqrtf(mag2);
      u = z.x * inv;
      v = z.y * inv;
    } else {                            // angle(0) = 0
      u = 1.0f;
      v = 0.0f;
    }
    phasor[(size_t)bc * T_LEN + t] = make_float2(u, v);
  }
}

// ---------------------------------------------------------------------------
// Kernel 2: register-tiled partial sums.
// Block = (chunk c, batch b). Stages 64 ch x 32 t phasors in LDS (stride 65,
// conflict-free). 256 threads as 16x16; each thread owns a 4x4 (i,j) tile.
// Accumulates over its assigned t-chunks; writes one float2 (num,den) partial
// per pair per block to ws.
// ---------------------------------------------------------------------------
__global__ __launch_bounds__(256) void wpli_partial_kernel(
    const float2* __restrict__ phasor, float2* __restrict__ part, int nchunk) {
  __shared__ float lu[32][65];
  __shared__ float lv[32][65];

  const int c = blockIdx.x;
  const int b = blockIdx.y;
  const int tid = threadIdx.x;
  const int tx = tid & 15;              // j-group
  const int ty = tid >> 4;              // i-group

  float accn[4][4] = {{0}}, accd[4][4] = {{0}};

  for (int sub = c; sub < T_LEN / 32; sub += nchunk) {
    const int t0 = sub * 32;
    __syncthreads();                    // protect LDS reuse across subs
    // stage: 64 ch x 32 t = 2048 float2, coalesced along t
    for (int idx = tid; idx < 2048; idx += 256) {
      const int ch = idx >> 5;
      const int tt = idx & 31;
      const float2 z = phasor[((size_t)(b * C_CH + ch)) * T_LEN + t0 + tt];
      lu[tt][ch] = z.x;
      lv[tt][ch] = z.y;
    }
    __syncthreads();

    for (int tt = 0; tt < 32; ++tt) {
      float ui[4], vi[4], uj[4], vj[4];
#pragma unroll
      for (int a = 0; a < 4; ++a) {
        ui[a] = lu[tt][ty * 4 + a];     // broadcast across tx
        vi[a] = lv[tt][ty * 4 + a];
        uj[a] = lu[tt][tx * 4 + a];     // 2-way (free) across wave
        vj[a] = lv[tt][tx * 4 + a];
      }
#pragma unroll
      for (int a = 0; a < 4; ++a)
#pragma unroll
        for (int e = 0; e < 4; ++e) {
          const float s = vi[a] * uj[e] - ui[a] * vj[e];
          accn[a][e] += s;
          accd[a][e] += fabsf(s);
        }
    }
  }

  float2* dstp = part + ((size_t)c * B_N + b) * (C_CH * C_CH);
#pragma unroll
  for (int a = 0; a < 4; ++a)
#pragma unroll
    for (int e = 0; e < 4; ++e) {
      const int i = ty * 4 + a;
      const int j = tx * 4 + e;
      dstp[i * C_CH + j] = make_float2(accn[a][e], accd[a][e]);
    }
}

// ---------------------------------------------------------------------------
// Kernel 3: reduce partials over chunks, finalize wpli.
// Diagonal: s == 0 exactly -> den == 0 -> 0 (matches eye mask + 1e-8 guard).
// ---------------------------------------------------------------------------
__global__ __launch_bounds__(256) void wpli_finalize_kernel(
    const float2* __restrict__ part, float* __restrict__ out, int nchunk) {
  const int idx = blockIdx.x * 256 + threadIdx.x;   // b*4096 + pair
  if (idx >= B_N * C_CH * C_CH) return;
  const int b = idx >> 12;
  const int pair = idx & 4095;
  float n = 0.0f, d = 0.0f;
  for (int c = 0; c < nchunk; ++c) {
    const float2 p = part[((size_t)c * B_N + b) * (C_CH * C_CH) + pair];
    n += p.x;
    d += p.y;
  }
  const int i = pair >> 6;
  const int j = pair & 63;
  float w = (d > 0.0f) ? fabsf(n) / d : 0.0f;
  if (i == j) w = 0.0f;
  out[idx] = w;
}

extern "C" void kernel_launch(void* const* d_in, const int* in_sizes, int n_in,
                              void* d_out, int out_size, void* d_ws, size_t ws_size,
                              hipStream_t stream) {
  const float* eeg = (const float*)d_in[0];
  float* out = (float*)d_out;

  const size_t phasor_bytes = (size_t)B_N * C_CH * T_LEN * sizeof(float2);  // 8 MB
  float2* phasor = (float2*)d_ws;
  float2* part = (float2*)((char*)d_ws + phasor_bytes);

  // adaptive chunk count: 64 chunks of 32 t if ws allows, else fewer blocks
  // (each block then accumulates several 32-t sub-chunks internally)
  const size_t per_chunk = (size_t)B_N * C_CH * C_CH * sizeof(float2);      // 256 KB
  const size_t avail = (ws_size > phasor_bytes) ? ws_size - phasor_bytes : 0;
  int nchunk = 64;
  while (nchunk > 1 && (size_t)nchunk * per_chunk > avail) nchunk >>= 1;

  hilbert_phasor_kernel<<<B_N * C_CH, 256, 0, stream>>>(eeg, phasor);

  dim3 grid(nchunk, B_N);
  wpli_partial_kernel<<<grid, 256, 0, stream>>>(phasor, part, nchunk);

  wpli_finalize_kernel<<<(B_N * C_CH * C_CH + 255) / 256, 256, 0, stream>>>(
      part, out, nchunk);
}

// Round 3
// 102.432 us; speedup vs baseline: 1.1816x; 1.0175x over previous
//
#include <hip/hip_runtime.h>
#include <math.h>

#define T_LEN 2048
#define C_CH  64
#define B_N   8
#define NCHUNK 64

__device__ __forceinline__ float2 cadd(float2 a, float2 b) { return make_float2(a.x + b.x, a.y + b.y); }
__device__ __forceinline__ float2 csub(float2 a, float2 b) { return make_float2(a.x - b.x, a.y - b.y); }

// ---------------------------------------------------------------------------
// Radix-4 Stockham stages with LDS twiddle table (forward-sign table; inverse
// conjugates at use). Table layout: per-stage base = (2048 - n) / 3, index p.
// ---------------------------------------------------------------------------
template <int SIGN>  // -1 = forward, +1 = inverse
__device__ __forceinline__ void fft_stages(float2*& src, float2*& dst, int tid,
                                           const float2* tw1, const float2* tw2,
                                           const float2* tw3) {
  for (int n = T_LEN, ls = 0; n >= 4; n >>= 2, ls += 2) {
    const int s = 1 << ls;
    const int m = n >> 2;
    const int base = (T_LEN - n) / 3;
    for (int idx = tid; idx < T_LEN / 4; idx += 256) {
      const int p = idx >> ls;
      const int q = idx & (s - 1);
      const int ib = q + s * p;
      const float2 a = src[ib];
      const float2 b = src[ib + s * m];
      const float2 c = src[ib + 2 * s * m];
      const float2 d = src[ib + 3 * s * m];
      const float2 t0 = cadd(a, c);
      const float2 t1 = csub(a, c);
      const float2 t2 = cadd(b, d);
      const float2 t3 = csub(b, d);
      const float2 y0 = cadd(t0, t2);
      const float2 r2 = csub(t0, t2);
      float2 r1, r3;
      if (SIGN < 0) {           // forward: r1 = t1 - i*t3, r3 = t1 + i*t3
        r1 = make_float2(t1.x + t3.y, t1.y - t3.x);
        r3 = make_float2(t1.x - t3.y, t1.y + t3.x);
      } else {                  // inverse: r1 = t1 + i*t3, r3 = t1 - i*t3
        r1 = make_float2(t1.x - t3.y, t1.y + t3.x);
        r3 = make_float2(t1.x + t3.y, t1.y - t3.x);
      }
      const float2 w1 = tw1[base + p];
      const float2 w2 = tw2[base + p];
      const float2 w3 = tw3[base + p];
      const float c1 = w1.x, s1 = (SIGN < 0) ? w1.y : -w1.y;
      const float c2 = w2.x, s2 = (SIGN < 0) ? w2.y : -w2.y;
      const float c3 = w3.x, s3 = (SIGN < 0) ? w3.y : -w3.y;
      const float2 y1 = make_float2(r1.x * c1 - r1.y * s1, r1.x * s1 + r1.y * c1);
      const float2 y2 = make_float2(r2.x * c2 - r2.y * s2, r2.x * s2 + r2.y * c2);
      const float2 y3 = make_float2(r3.x * c3 - r3.y * s3, r3.x * s3 + r3.y * c3);
      const int ob = q + s * 4 * p;
      dst[ob]         = y0;
      dst[ob + s]     = y1;
      dst[ob + 2 * s] = y2;
      dst[ob + 3 * s] = y3;
    }
    __syncthreads();
    float2* tmp = src; src = dst; dst = tmp;
  }
  // final radix-2 stage: n = 2, s = 1024, twiddle = 1
  for (int q = tid; q < T_LEN / 2; q += 256) {
    const float2 a = src[q];
    const float2 b = src[q + T_LEN / 2];
    dst[q]             = cadd(a, b);
    dst[q + T_LEN / 2] = csub(a, b);
  }
  __syncthreads();
  float2* tmp = src; src = dst; dst = tmp;
}

// ---------------------------------------------------------------------------
// Kernel 1: per-(b,c) Hilbert via radix-4 LDS FFT with LDS twiddles.
// Filter: spec[k<1024] *= 2, spec[k>=1024] = 0 (reference-faithful).
// 1/N ifft scale cancels in phasor normalization.
// ---------------------------------------------------------------------------
__global__ __launch_bounds__(256) void hilbert_phasor_kernel(
    const float* __restrict__ x, float2* __restrict__ phasor) {
  __shared__ float2 bufA[T_LEN];
  __shared__ float2 bufB[T_LEN];
  __shared__ float2 tw1[682], tw2[682], tw3[682];

  const int bc = blockIdx.x;
  const int tid = threadIdx.x;
  const float* sig = x + (size_t)bc * T_LEN;

  // build forward twiddle table: stages n = 2048,512,128,32,8
  for (int idx = tid; idx < 682; idx += 256) {
    int n, p;
    if (idx < 512)      { n = 2048; p = idx; }
    else if (idx < 640) { n = 512;  p = idx - 512; }
    else if (idx < 672) { n = 128;  p = idx - 640; }
    else if (idx < 680) { n = 32;   p = idx - 672; }
    else                { n = 8;    p = idx - 680; }
    const float th = -6.28318530717958647692f * (float)p / (float)n;
    float sn, cs;
    sincosf(th, &sn, &cs);        tw1[idx] = make_float2(cs, sn);
    sincosf(2.0f * th, &sn, &cs); tw2[idx] = make_float2(cs, sn);
    sincosf(3.0f * th, &sn, &cs); tw3[idx] = make_float2(cs, sn);
  }

  for (int t = tid; t < T_LEN; t += 256)
    bufA[t] = make_float2(sig[t], 0.0f);
  __syncthreads();

  float2* src = bufA;
  float2* dst = bufB;

  fft_stages<-1>(src, dst, tid, tw1, tw2, tw3);   // forward FFT

  for (int k = tid; k < T_LEN; k += 256) {
    const float f = (k < T_LEN / 2) ? 2.0f : 0.0f;
    src[k].x *= f;
    src[k].y *= f;
  }
  __syncthreads();

  fft_stages<1>(src, dst, tid, tw1, tw2, tw3);    // inverse FFT (unscaled)

  for (int t = tid; t < T_LEN; t += 256) {
    const float2 z = src[t];
    const float mag2 = z.x * z.x + z.y * z.y;
    float u, v;
    if (mag2 > 0.0f) {
      const float inv = rsqrtf(mag2);
      u = z.x * inv;
      v = z.y * inv;
    } else {                      // angle(0) = 0
      u = 1.0f;
      v = 0.0f;
    }
    phasor[(size_t)bc * T_LEN + t] = make_float2(u, v);
  }
}

// ---------------------------------------------------------------------------
// Kernel 2: register-tiled partial sums, interleaved-float2 LDS staging.
// Block = (chunk c, batch b). 256 threads as 16x16; 4x4 (i,j) tile each.
// ---------------------------------------------------------------------------
__global__ __launch_bounds__(256) void wpli_partial_kernel(
    const float2* __restrict__ phasor, float2* __restrict__ part, int nchunk) {
  __shared__ float2 lz[32][65];

  const int c = blockIdx.x;
  const int b = blockIdx.y;
  const int tid = threadIdx.x;
  const int tx = tid & 15;              // j-group
  const int ty = tid >> 4;              // i-group

  float accn[4][4] = {{0}}, accd[4][4] = {{0}};

  for (int sub = c; sub < T_LEN / 32; sub += nchunk) {
    const int t0 = sub * 32;
    __syncthreads();
    for (int idx = tid; idx < 2048; idx += 256) {
      const int ch = idx >> 5;
      const int tt = idx & 31;
      lz[tt][ch] = phasor[((size_t)(b * C_CH + ch)) * T_LEN + t0 + tt];
    }
    __syncthreads();

    for (int tt = 0; tt < 32; ++tt) {
      float2 zi[4], zj[4];
#pragma unroll
      for (int a = 0; a < 4; ++a) {
        zi[a] = lz[tt][ty * 4 + a];     // broadcast across tx
        zj[a] = lz[tt][tx * 4 + a];
      }
#pragma unroll
      for (int a = 0; a < 4; ++a)
#pragma unroll
        for (int e = 0; e < 4; ++e) {
          const float s = zi[a].y * zj[e].x - zi[a].x * zj[e].y;
          accn[a][e] += s;
          accd[a][e] += fabsf(s);
        }
    }
  }

  float2* dstp = part + ((size_t)c * B_N + b) * (C_CH * C_CH);
#pragma unroll
  for (int a = 0; a < 4; ++a)
#pragma unroll
    for (int e = 0; e < 4; ++e) {
      const int i = ty * 4 + a;
      const int j = tx * 4 + e;
      dstp[i * C_CH + j] = make_float2(accn[a][e], accd[a][e]);
    }
}

// ---------------------------------------------------------------------------
// Kernel 3: reduce partials over chunks, finalize wpli.
// Diagonal: s == 0 exactly -> den == 0 -> 0 (matches eye mask + 1e-8 guard).
// ---------------------------------------------------------------------------
__global__ __launch_bounds__(256) void wpli_finalize_kernel(
    const float2* __restrict__ part, float* __restrict__ out, int nchunk) {
  const int idx = blockIdx.x * 256 + threadIdx.x;   // b*4096 + pair
  if (idx >= B_N * C_CH * C_CH) return;
  const int b = idx >> 12;
  const int pair = idx & 4095;
  float n = 0.0f, d = 0.0f;
  for (int c = 0; c < nchunk; ++c) {
    const float2 p = part[((size_t)c * B_N + b) * (C_CH * C_CH) + pair];
    n += p.x;
    d += p.y;
  }
  const int i = pair >> 6;
  const int j = pair & 63;
  float w = (d > 0.0f) ? fabsf(n) / d : 0.0f;
  if (i == j) w = 0.0f;
  out[idx] = w;
}

extern "C" void kernel_launch(void* const* d_in, const int* in_sizes, int n_in,
                              void* d_out, int out_size, void* d_ws, size_t ws_size,
                              hipStream_t stream) {
  const float* eeg = (const float*)d_in[0];
  float* out = (float*)d_out;

  const size_t phasor_bytes = (size_t)B_N * C_CH * T_LEN * sizeof(float2);  // 8 MB
  float2* phasor = (float2*)d_ws;
  float2* part = (float2*)((char*)d_ws + phasor_bytes);

  const size_t per_chunk = (size_t)B_N * C_CH * C_CH * sizeof(float2);      // 256 KB
  const size_t avail = (ws_size > phasor_bytes) ? ws_size - phasor_bytes : 0;
  int nchunk = NCHUNK;
  while (nchunk > 1 && (size_t)nchunk * per_chunk > avail) nchunk >>= 1;

  hilbert_phasor_kernel<<<B_N * C_CH, 256, 0, stream>>>(eeg, phasor);

  dim3 grid(nchunk, B_N);
  wpli_partial_kernel<<<grid, 256, 0, stream>>>(phasor, part, nchunk);

  wpli_finalize_kernel<<<(B_N * C_CH * C_CH + 255) / 256, 256, 0, stream>>>(
      part, out, nchunk);
}

// Round 4
// 99.849 us; speedup vs baseline: 1.2121x; 1.0259x over previous
//
#include <hip/hip_runtime.h>
#include <math.h>

#define T_LEN 2048
#define C_CH  64
#define B_N   8
#define NCHUNK 64

// diagonal skew: breaks power-of-2 write strides in the Stockham stages
#define IX(a) ((a) + ((a) >> 4))

__device__ __forceinline__ float2 cadd(float2 a, float2 b) { return make_float2(a.x + b.x, a.y + b.y); }
__device__ __forceinline__ float2 csub(float2 a, float2 b) { return make_float2(a.x - b.x, a.y - b.y); }
__device__ __forceinline__ float2 cmul(float2 a, float2 w) {
  return make_float2(a.x * w.x - a.y * w.y, a.x * w.y + a.y * w.x);
}

// ---------------------------------------------------------------------------
// Generic radix-4 Stockham stages for n = 512,128,32,8 (s = 4,16,64,256).
// Reads are contiguous (idx, +512, +1024, +1536); writes skewed via IX.
// Single twiddle table (forward sign); w2 = w1^2, w3 = w2*w1 in registers.
// ---------------------------------------------------------------------------
template <int SIGN>  // -1 = forward, +1 = inverse
__device__ __forceinline__ void radix4_stages(float2*& src, float2*& dst,
                                              int tid, const float2* tw) {
  for (int n = 512, ls = 2; n >= 8; n >>= 2, ls += 2) {
    const int s = 1 << ls;
    const int base = (T_LEN - n) / 3;   // 512, 640, 672, 680
    for (int idx = tid; idx < 512; idx += 256) {
      const int p = idx >> ls;
      const int q = idx & (s - 1);
      const float2 a = src[IX(idx)];
      const float2 b = src[IX(idx + 512)];
      const float2 c = src[IX(idx + 1024)];
      const float2 d = src[IX(idx + 1536)];
      const float2 t0 = cadd(a, c);
      const float2 t1 = csub(a, c);
      const float2 t2 = cadd(b, d);
      const float2 t3 = csub(b, d);
      const float2 y0 = cadd(t0, t2);
      const float2 r2 = csub(t0, t2);
      float2 r1, r3;
      if (SIGN < 0) {                   // forward: r1 = t1 - i*t3
        r1 = make_float2(t1.x + t3.y, t1.y - t3.x);
        r3 = make_float2(t1.x - t3.y, t1.y + t3.x);
      } else {                          // inverse: r1 = t1 + i*t3
        r1 = make_float2(t1.x - t3.y, t1.y + t3.x);
        r3 = make_float2(t1.x + t3.y, t1.y - t3.x);
      }
      float2 w1 = tw[base + p];
      if (SIGN > 0) w1.y = -w1.y;       // conjugate for inverse
      const float2 w2 = make_float2(w1.x * w1.x - w1.y * w1.y, 2.0f * w1.x * w1.y);
      const float2 w3 = cmul(w2, w1);
      const int ob = q + 4 * s * p;
      dst[IX(ob)]         = y0;
      dst[IX(ob + s)]     = cmul(r1, w1);
      dst[IX(ob + 2 * s)] = cmul(r2, w2);
      dst[IX(ob + 3 * s)] = cmul(r3, w3);
    }
    __syncthreads();
    float2* tmp = src; src = dst; dst = tmp;
  }
}

// ---------------------------------------------------------------------------
// Kernel 1: per-(b,c) Hilbert -> unit phasors.
// Pipeline: fwd st1 (fused real global load) -> fwd st2..5 -> fwd radix-2 ->
// inv st1 (fused filter: k>=1024 zeroed, x2 dropped) -> inv st2..5 ->
// inv radix-2 fused with phasor normalize+store.
// Global scales (2 from filter, 1/N from ifft) cancel in normalization.
// ---------------------------------------------------------------------------
__global__ __launch_bounds__(256) void hilbert_phasor_kernel(
    const float* __restrict__ x, float2* __restrict__ phasor) {
  __shared__ float2 bufA[IX(T_LEN - 1) + 1];
  __shared__ float2 bufB[IX(T_LEN - 1) + 1];
  __shared__ float2 tw[682];

  const int bc = blockIdx.x;
  const int tid = threadIdx.x;
  const float* sig = x + (size_t)bc * T_LEN;

  // forward twiddle table: stage bases 0(n=2048),512(512),640(128),672(32),680(8)
  for (int idx = tid; idx < 682; idx += 256) {
    int n, p;
    if (idx < 512)      { n = 2048; p = idx; }
    else if (idx < 640) { n = 512;  p = idx - 512; }
    else if (idx < 672) { n = 128;  p = idx - 640; }
    else if (idx < 680) { n = 32;   p = idx - 672; }
    else                { n = 8;    p = idx - 680; }
    float sn, cs;
    sincosf(-6.28318530717958647692f * (float)p / (float)n, &sn, &cs);
    tw[idx] = make_float2(cs, sn);
  }
  // NOTE: fwd stage 1 reads tw[idx] for idx = tid, tid+256 — exactly the
  // entries this thread wrote above, so no barrier needed before stage 1.

  float2* src = bufA;   // stage 1 writes into bufA
  float2* dst = bufB;

  // ---- forward stage 1 (n=2048, s=1): real input straight from global ----
  for (int idx = tid; idx < 512; idx += 256) {
    const float a = sig[idx];
    const float b = sig[idx + 512];
    const float c = sig[idx + 1024];
    const float d = sig[idx + 1536];
    const float t0 = a + c, t1 = a - c, t2 = b + d, t3 = b - d;
    const float2 w1 = tw[idx];
    const float2 w2 = make_float2(w1.x * w1.x - w1.y * w1.y, 2.0f * w1.x * w1.y);
    const float2 w3 = cmul(w2, w1);
    const float2 r1 = make_float2(t1, -t3);   // t1 - i*t3 (real t1,t3)
    const float2 r3 = make_float2(t1,  t3);
    src[IX(4 * idx)]     = make_float2(t0 + t2, 0.0f);
    src[IX(4 * idx + 1)] = cmul(r1, w1);
    src[IX(4 * idx + 2)] = make_float2((t0 - t2) * w2.x, (t0 - t2) * w2.y);
    src[IX(4 * idx + 3)] = cmul(r3, w3);
  }
  __syncthreads();

  radix4_stages<-1>(src, dst, tid, tw);       // fwd st2..5 (result in src)

  // ---- forward final radix-2 (s=1024, twiddle = 1) ----
  for (int q = tid; q < 1024; q += 256) {
    const float2 a = src[IX(q)];
    const float2 b = src[IX(q + 1024)];
    dst[IX(q)]        = cadd(a, b);
    dst[IX(q + 1024)] = csub(a, b);
  }
  __syncthreads();
  { float2* tmp = src; src = dst; dst = tmp; }   // spectrum (natural order) in src

  // ---- inverse stage 1 (n=2048, s=1) fused with analytic filter ----
  // spec[k>=1024] = 0  =>  c = d = 0; uniform x2 dropped (cancels).
  for (int idx = tid; idx < 512; idx += 256) {
    const float2 a = src[IX(idx)];
    const float2 b = src[IX(idx + 512)];
    float2 w1 = tw[idx]; w1.y = -w1.y;          // conjugate
    const float2 w2 = make_float2(w1.x * w1.x - w1.y * w1.y, 2.0f * w1.x * w1.y);
    const float2 w3 = cmul(w2, w1);
    const float2 y0 = cadd(a, b);
    const float2 r2 = csub(a, b);
    const float2 r1 = make_float2(a.x - b.y, a.y + b.x);   // a + i*b
    const float2 r3 = make_float2(a.x + b.y, a.y - b.x);   // a - i*b
    dst[IX(4 * idx)]     = y0;
    dst[IX(4 * idx + 1)] = cmul(r1, w1);
    dst[IX(4 * idx + 2)] = cmul(r2, w2);
    dst[IX(4 * idx + 3)] = cmul(r3, w3);
  }
  __syncthreads();
  { float2* tmp = src; src = dst; dst = tmp; }

  radix4_stages<1>(src, dst, tid, tw);        // inv st2..5 (result in src)

  // ---- inverse final radix-2 fused with phasor normalize + store ----
  for (int q = tid; q < 1024; q += 256) {
    const float2 a = src[IX(q)];
    const float2 b = src[IX(q + 1024)];
    const float2 zs = cadd(a, b);
    const float2 zd = csub(a, b);
    float2 outv[2] = {zs, zd};
    int    outq[2] = {q, q + 1024};
#pragma unroll
    for (int k = 0; k < 2; ++k) {
      const float2 z = outv[k];
      const float mag2 = z.x * z.x + z.y * z.y;
      float u, v;
      if (mag2 > 0.0f) {
        const float inv = rsqrtf(mag2);
        u = z.x * inv;
        v = z.y * inv;
      } else {                        // angle(0) = 0
        u = 1.0f;
        v = 0.0f;
      }
      phasor[(size_t)bc * T_LEN + outq[k]] = make_float2(u, v);
    }
  }
}

// ---------------------------------------------------------------------------
// Kernel 2: register-tiled partial sums (unchanged from R3 — verified).
// ---------------------------------------------------------------------------
__global__ __launch_bounds__(256) void wpli_partial_kernel(
    const float2* __restrict__ phasor, float2* __restrict__ part, int nchunk) {
  __shared__ float2 lz[32][65];

  const int c = blockIdx.x;
  const int b = blockIdx.y;
  const int tid = threadIdx.x;
  const int tx = tid & 15;
  const int ty = tid >> 4;

  float accn[4][4] = {{0}}, accd[4][4] = {{0}};

  for (int sub = c; sub < T_LEN / 32; sub += nchunk) {
    const int t0 = sub * 32;
    __syncthreads();
    for (int idx = tid; idx < 2048; idx += 256) {
      const int ch = idx >> 5;
      const int tt = idx & 31;
      lz[tt][ch] = phasor[((size_t)(b * C_CH + ch)) * T_LEN + t0 + tt];
    }
    __syncthreads();

    for (int tt = 0; tt < 32; ++tt) {
      float2 zi[4], zj[4];
#pragma unroll
      for (int a = 0; a < 4; ++a) {
        zi[a] = lz[tt][ty * 4 + a];
        zj[a] = lz[tt][tx * 4 + a];
      }
#pragma unroll
      for (int a = 0; a < 4; ++a)
#pragma unroll
        for (int e = 0; e < 4; ++e) {
          const float s = zi[a].y * zj[e].x - zi[a].x * zj[e].y;
          accn[a][e] += s;
          accd[a][e] += fabsf(s);
        }
    }
  }

  float2* dstp = part + ((size_t)c * B_N + b) * (C_CH * C_CH);
#pragma unroll
  for (int a = 0; a < 4; ++a)
#pragma unroll
    for (int e = 0; e < 4; ++e) {
      const int i = ty * 4 + a;
      const int j = tx * 4 + e;
      dstp[i * C_CH + j] = make_float2(accn[a][e], accd[a][e]);
    }
}

// ---------------------------------------------------------------------------
// Kernel 3: reduce partials, finalize wpli (unchanged from R3 — verified).
// ---------------------------------------------------------------------------
__global__ __launch_bounds__(256) void wpli_finalize_kernel(
    const float2* __restrict__ part, float* __restrict__ out, int nchunk) {
  const int idx = blockIdx.x * 256 + threadIdx.x;
  if (idx >= B_N * C_CH * C_CH) return;
  const int b = idx >> 12;
  const int pair = idx & 4095;
  float n = 0.0f, d = 0.0f;
  for (int c = 0; c < nchunk; ++c) {
    const float2 p = part[((size_t)c * B_N + b) * (C_CH * C_CH) + pair];
    n += p.x;
    d += p.y;
  }
  const int i = pair >> 6;
  const int j = pair & 63;
  float w = (d > 0.0f) ? fabsf(n) / d : 0.0f;
  if (i == j) w = 0.0f;
  out[idx] = w;
}

extern "C" void kernel_launch(void* const* d_in, const int* in_sizes, int n_in,
                              void* d_out, int out_size, void* d_ws, size_t ws_size,
                              hipStream_t stream) {
  const float* eeg = (const float*)d_in[0];
  float* out = (float*)d_out;

  const size_t phasor_bytes = (size_t)B_N * C_CH * T_LEN * sizeof(float2);  // 8 MB
  float2* phasor = (float2*)d_ws;
  float2* part = (float2*)((char*)d_ws + phasor_bytes);

  const size_t per_chunk = (size_t)B_N * C_CH * C_CH * sizeof(float2);      // 256 KB
  const size_t avail = (ws_size > phasor_bytes) ? ws_size - phasor_bytes : 0;
  int nchunk = NCHUNK;
  while (nchunk > 1 && (size_t)nchunk * per_chunk > avail) nchunk >>= 1;

  hilbert_phasor_kernel<<<B_N * C_CH, 256, 0, stream>>>(eeg, phasor);

  dim3 grid(nchunk, B_N);
  wpli_partial_kernel<<<grid, 256, 0, stream>>>(phasor, part, nchunk);

  wpli_finalize_kernel<<<(B_N * C_CH * C_CH + 255) / 256, 256, 0, stream>>>(
      part, out, nchunk);
}

// Round 5
// 97.757 us; speedup vs baseline: 1.2381x; 1.0214x over previous
//
#include <hip/hip_runtime.h>
#include <math.h>

#define T_LEN 2048
#define C_CH  64
#define B_N   8
#define NCHUNK 64

// diagonal skew: breaks power-of-2 write strides in the Stockham stages
#define IX(a) ((a) + ((a) >> 4))

__device__ __forceinline__ float2 cadd(float2 a, float2 b) { return make_float2(a.x + b.x, a.y + b.y); }
__device__ __forceinline__ float2 csub(float2 a, float2 b) { return make_float2(a.x - b.x, a.y - b.y); }
__device__ __forceinline__ float2 cmul(float2 a, float2 w) {
  return make_float2(a.x * w.x - a.y * w.y, a.x * w.y + a.y * w.x);
}

// ---------------------------------------------------------------------------
// Radix-4 Stockham stages for n = 512,128,32,8 (s = 4,16,64,256).
// Reads contiguous; writes skewed via IX. Single twiddle table (fwd sign);
// w2 = w1^2, w3 = w2*w1 in registers.
// ---------------------------------------------------------------------------
template <int SIGN>  // -1 = forward, +1 = inverse
__device__ __forceinline__ void radix4_stages(float2*& src, float2*& dst,
                                              int tid, const float2* tw) {
  for (int n = 512, ls = 2; n >= 8; n >>= 2, ls += 2) {
    const int s = 1 << ls;
    const int base = (T_LEN - n) / 3;   // 512, 640, 672, 680
    for (int idx = tid; idx < 512; idx += 256) {
      const int p = idx >> ls;
      const int q = idx & (s - 1);
      const float2 a = src[IX(idx)];
      const float2 b = src[IX(idx + 512)];
      const float2 c = src[IX(idx + 1024)];
      const float2 d = src[IX(idx + 1536)];
      const float2 t0 = cadd(a, c);
      const float2 t1 = csub(a, c);
      const float2 t2 = cadd(b, d);
      const float2 t3 = csub(b, d);
      const float2 y0 = cadd(t0, t2);
      const float2 r2 = csub(t0, t2);
      float2 r1, r3;
      if (SIGN < 0) {                   // forward: r1 = t1 - i*t3
        r1 = make_float2(t1.x + t3.y, t1.y - t3.x);
        r3 = make_float2(t1.x - t3.y, t1.y + t3.x);
      } else {                          // inverse: r1 = t1 + i*t3
        r1 = make_float2(t1.x - t3.y, t1.y + t3.x);
        r3 = make_float2(t1.x + t3.y, t1.y - t3.x);
      }
      float2 w1 = tw[base + p];
      if (SIGN > 0) w1.y = -w1.y;       // conjugate for inverse
      const float2 w2 = make_float2(w1.x * w1.x - w1.y * w1.y, 2.0f * w1.x * w1.y);
      const float2 w3 = cmul(w2, w1);
      const int ob = q + 4 * s * p;
      dst[IX(ob)]         = y0;
      dst[IX(ob + s)]     = cmul(r1, w1);
      dst[IX(ob + 2 * s)] = cmul(r2, w2);
      dst[IX(ob + 3 * s)] = cmul(r3, w3);
    }
    __syncthreads();
    float2* tmp = src; src = dst; dst = tmp;
  }
}

// ---------------------------------------------------------------------------
// Kernel 1: per-(b,c) Hilbert -> unit phasors (unchanged from R4 — verified).
// ---------------------------------------------------------------------------
__global__ __launch_bounds__(256) void hilbert_phasor_kernel(
    const float* __restrict__ x, float2* __restrict__ phasor) {
  __shared__ float2 bufA[IX(T_LEN - 1) + 1];
  __shared__ float2 bufB[IX(T_LEN - 1) + 1];
  __shared__ float2 tw[682];

  const int bc = blockIdx.x;
  const int tid = threadIdx.x;
  const float* sig = x + (size_t)bc * T_LEN;

  for (int idx = tid; idx < 682; idx += 256) {
    int n, p;
    if (idx < 512)      { n = 2048; p = idx; }
    else if (idx < 640) { n = 512;  p = idx - 512; }
    else if (idx < 672) { n = 128;  p = idx - 640; }
    else if (idx < 680) { n = 32;   p = idx - 672; }
    else                { n = 8;    p = idx - 680; }
    float sn, cs;
    sincosf(-6.28318530717958647692f * (float)p / (float)n, &sn, &cs);
    tw[idx] = make_float2(cs, sn);
  }
  // fwd stage 1 reads tw[idx] for idx = tid, tid+256 — entries this thread
  // wrote above, so no barrier needed before stage 1.

  float2* src = bufA;
  float2* dst = bufB;

  // ---- forward stage 1 (n=2048, s=1): real input straight from global ----
  for (int idx = tid; idx < 512; idx += 256) {
    const float a = sig[idx];
    const float b = sig[idx + 512];
    const float c = sig[idx + 1024];
    const float d = sig[idx + 1536];
    const float t0 = a + c, t1 = a - c, t2 = b + d, t3 = b - d;
    const float2 w1 = tw[idx];
    const float2 w2 = make_float2(w1.x * w1.x - w1.y * w1.y, 2.0f * w1.x * w1.y);
    const float2 w3 = cmul(w2, w1);
    const float2 r1 = make_float2(t1, -t3);
    const float2 r3 = make_float2(t1,  t3);
    src[IX(4 * idx)]     = make_float2(t0 + t2, 0.0f);
    src[IX(4 * idx + 1)] = cmul(r1, w1);
    src[IX(4 * idx + 2)] = make_float2((t0 - t2) * w2.x, (t0 - t2) * w2.y);
    src[IX(4 * idx + 3)] = cmul(r3, w3);
  }
  __syncthreads();

  radix4_stages<-1>(src, dst, tid, tw);

  for (int q = tid; q < 1024; q += 256) {
    const float2 a = src[IX(q)];
    const float2 b = src[IX(q + 1024)];
    dst[IX(q)]        = cadd(a, b);
    dst[IX(q + 1024)] = csub(a, b);
  }
  __syncthreads();
  { float2* tmp = src; src = dst; dst = tmp; }

  // ---- inverse stage 1 fused with analytic filter (c = d = 0) ----
  for (int idx = tid; idx < 512; idx += 256) {
    const float2 a = src[IX(idx)];
    const float2 b = src[IX(idx + 512)];
    float2 w1 = tw[idx]; w1.y = -w1.y;
    const float2 w2 = make_float2(w1.x * w1.x - w1.y * w1.y, 2.0f * w1.x * w1.y);
    const float2 w3 = cmul(w2, w1);
    const float2 y0 = cadd(a, b);
    const float2 r2 = csub(a, b);
    const float2 r1 = make_float2(a.x - b.y, a.y + b.x);
    const float2 r3 = make_float2(a.x + b.y, a.y - b.x);
    dst[IX(4 * idx)]     = y0;
    dst[IX(4 * idx + 1)] = cmul(r1, w1);
    dst[IX(4 * idx + 2)] = cmul(r2, w2);
    dst[IX(4 * idx + 3)] = cmul(r3, w3);
  }
  __syncthreads();
  { float2* tmp = src; src = dst; dst = tmp; }

  radix4_stages<1>(src, dst, tid, tw);

  for (int q = tid; q < 1024; q += 256) {
    const float2 a = src[IX(q)];
    const float2 b = src[IX(q + 1024)];
    const float2 zs = cadd(a, b);
    const float2 zd = csub(a, b);
    float2 outv[2] = {zs, zd};
    int    outq[2] = {q, q + 1024};
#pragma unroll
    for (int k = 0; k < 2; ++k) {
      const float2 z = outv[k];
      const float mag2 = z.x * z.x + z.y * z.y;
      float u, v;
      if (mag2 > 0.0f) {
        const float inv = rsqrtf(mag2);
        u = z.x * inv;
        v = z.y * inv;
      } else {
        u = 1.0f;
        v = 0.0f;
      }
      phasor[(size_t)bc * T_LEN + outq[k]] = make_float2(u, v);
    }
  }
}

// ---------------------------------------------------------------------------
// Kernel 2: gap-folded partial sums — HALF the pair work.
// Cell (r,c), r in [0,64), c in [0,32) computes ordered pair (r, (r+1+c)&63):
// every ordered pair with gap 1..32 exactly once (s(j,i) = -s(i,j) recovers
// the rest). Thread = 4 rows x 2 cols: 4 zi + 5 consecutive zj reads per tt
// for 8 pairs. Slot layout: part[(chunk*B + b)*2048 + r*32 + c].
// ---------------------------------------------------------------------------
__global__ __launch_bounds__(256) void wpli_partial_kernel(
    const float2* __restrict__ phasor, float2* __restrict__ part, int nchunk) {
  __shared__ float2 lz[32][65];

  const int c = blockIdx.x;
  const int b = blockIdx.y;
  const int tid = threadIdx.x;
  const int tx = tid & 15;              // col group: c in [tx*2, tx*2+1]
  const int ty = tid >> 4;              // row group: r in [ty*4, ty*4+3]

  float accn[4][2] = {{0}}, accd[4][2] = {{0}};

  for (int sub = c; sub < T_LEN / 32; sub += nchunk) {
    const int t0 = sub * 32;
    __syncthreads();
    for (int idx = tid; idx < 2048; idx += 256) {
      const int ch = idx >> 5;
      const int tt = idx & 31;
      lz[tt][ch] = phasor[((size_t)(b * C_CH + ch)) * T_LEN + t0 + tt];
    }
    __syncthreads();

    const int jbase = ty * 4 + tx * 2 + 1;    // j-channel = (jbase + a + e) & 63
    for (int tt = 0; tt < 32; ++tt) {
      float2 zi[4], zw[5];
#pragma unroll
      for (int a = 0; a < 4; ++a) zi[a] = lz[tt][ty * 4 + a];
#pragma unroll
      for (int k = 0; k < 5; ++k) zw[k] = lz[tt][(jbase + k) & 63];
#pragma unroll
      for (int a = 0; a < 4; ++a)
#pragma unroll
        for (int e = 0; e < 2; ++e) {
          const float2 zj = zw[a + e];
          const float s = zi[a].y * zj.x - zi[a].x * zj.y;
          accn[a][e] += s;
          accd[a][e] += fabsf(s);
        }
    }
  }

  float2* dstp = part + ((size_t)c * B_N + b) * 2048;
#pragma unroll
  for (int a = 0; a < 4; ++a)
#pragma unroll
    for (int e = 0; e < 2; ++e) {
      const int r  = ty * 4 + a;
      const int cc = tx * 2 + e;
      dstp[r * 32 + cc] = make_float2(accn[a][e], accd[a][e]);
    }
}

// ---------------------------------------------------------------------------
// Kernel 3: reduce partials over chunks, finalize wpli with gap mirroring.
// out(i,j): g = (j-i)&63. g==0 -> 0. g<=32 -> slot (i, g-1); g>32 -> slot
// (j, 63-g) which holds the (j,i) sums: |num| and den are pair-symmetric.
// ---------------------------------------------------------------------------
__global__ __launch_bounds__(256) void wpli_finalize_kernel(
    const float2* __restrict__ part, float* __restrict__ out, int nchunk) {
  const int idx = blockIdx.x * 256 + threadIdx.x;   // b*4096 + i*64 + j
  if (idx >= B_N * C_CH * C_CH) return;
  const int b = idx >> 12;
  const int pair = idx & 4095;
  const int i = pair >> 6;
  const int j = pair & 63;
  const int g = (j - i) & 63;
  float w = 0.0f;
  if (g != 0) {
    int r, cc;
    if (g <= 32) { r = i; cc = g - 1; }
    else         { r = j; cc = 63 - g; }
    const int slot = r * 32 + cc;
    float n = 0.0f, d = 0.0f;
    for (int c = 0; c < nchunk; ++c) {
      const float2 p = part[((size_t)c * B_N + b) * 2048 + slot];
      n += p.x;
      d += p.y;
    }
    w = (d > 0.0f) ? fabsf(n) / d : 0.0f;
  }
  out[idx] = w;
}

extern "C" void kernel_launch(void* const* d_in, const int* in_sizes, int n_in,
                              void* d_out, int out_size, void* d_ws, size_t ws_size,
                              hipStream_t stream) {
  const float* eeg = (const float*)d_in[0];
  float* out = (float*)d_out;

  const size_t phasor_bytes = (size_t)B_N * C_CH * T_LEN * sizeof(float2);  // 8 MB
  float2* phasor = (float2*)d_ws;
  float2* part = (float2*)((char*)d_ws + phasor_bytes);

  const size_t per_chunk = (size_t)B_N * 2048 * sizeof(float2);             // 128 KB
  const size_t avail = (ws_size > phasor_bytes) ? ws_size - phasor_bytes : 0;
  int nchunk = NCHUNK;
  while (nchunk > 1 && (size_t)nchunk * per_chunk > avail) nchunk >>= 1;

  hilbert_phasor_kernel<<<B_N * C_CH, 256, 0, stream>>>(eeg, phasor);

  dim3 grid(nchunk, B_N);
  wpli_partial_kernel<<<grid, 256, 0, stream>>>(phasor, part, nchunk);

  wpli_finalize_kernel<<<(B_N * C_CH * C_CH + 255) / 256, 256, 0, stream>>>(
      part, out, nchunk);
}